// Round 1
// baseline (1493.959 us; speedup 1.0000x reference)
//
#include <hip/hip_runtime.h>

#define F_IN 61
#define H 32

// ---------- precompute ----------
__global__ __launch_bounds__(256) void deg_kernel(const int* __restrict__ ei,
                                                  float* __restrict__ deg, int E) {
    int e = blockIdx.x * 256 + threadIdx.x;
    if (e < E) atomicAdd(&deg[ei[E + e]], 1.0f);
}

__global__ __launch_bounds__(256) void dinv_kernel(float* __restrict__ deg, int N) {
    int i = blockIdx.x * 256 + threadIdx.x;
    if (i < N) deg[i] = rsqrtf(deg[i] + 1.0f);   // +1 for self-loop
}

__global__ __launch_bounds__(256) void norm_kernel(const int* __restrict__ ei,
                                                   const float* __restrict__ dinv,
                                                   float* __restrict__ norm, int E) {
    int e = blockIdx.x * 256 + threadIdx.x;
    if (e < E) norm[e] = dinv[ei[e]] * dinv[ei[E + e]];
}

// ---------- dense layers ----------
// Layer 1: x (N x 61) @ W (61 x 32) -> h (N x 32). 8 nodes per 256-thread block.
__global__ __launch_bounds__(256) void gemm1_kernel(const float* __restrict__ x,
                                                    const float* __restrict__ W,
                                                    float* __restrict__ h, int N) {
    __shared__ float Ws[F_IN * H];
    int tid = threadIdx.x;
    for (int i = tid; i < F_IN * H; i += 256) Ws[i] = W[i];
    __syncthreads();
    int node = blockIdx.x * 8 + (tid >> 5);
    int f = tid & 31;
    if (node < N) {
        const float* xr = x + (long long)node * F_IN;
        float s = 0.f;
        #pragma unroll
        for (int k = 0; k < F_IN; k++) s += xr[k] * Ws[k * H + f];
        h[(long long)node * H + f] = s;
    }
}

// Hidden layers: x (N x 32) @ W (32 x 32) -> h (N x 32)
__global__ __launch_bounds__(256) void gemmh_kernel(const float* __restrict__ x,
                                                    const float* __restrict__ W,
                                                    float* __restrict__ h, int N) {
    __shared__ float Ws[H * H];
    int tid = threadIdx.x;
    for (int i = tid; i < H * H; i += 256) Ws[i] = W[i];
    __syncthreads();
    int node = blockIdx.x * 8 + (tid >> 5);
    int f = tid & 31;
    if (node < N) {
        const float* xr = x + (long long)node * H;
        float s = 0.f;
        #pragma unroll
        for (int k = 0; k < H; k++) s += xr[k] * Ws[k * H + f];
        h[(long long)node * H + f] = s;
    }
}

// ---------- edge aggregation ----------
// one thread per (edge, feature): agg[dst][f] += h[src][f] * norm[e]
__global__ __launch_bounds__(256) void agg_kernel(const int* __restrict__ ei,
                                                  const float* __restrict__ norm,
                                                  const float* __restrict__ h,
                                                  float* __restrict__ agg, int E) {
    long long idx = (long long)blockIdx.x * 256 + threadIdx.x;
    if (idx >= (long long)E * H) return;
    int e = (int)(idx >> 5);
    int f = (int)(idx & 31);
    int s = ei[e];
    int d = ei[E + e];
    float v = h[(long long)s * H + f] * norm[e];
    atomicAdd(&agg[(long long)d * H + f], v);
}

// self-loop term + bias + relu, in place on agg
__global__ __launch_bounds__(256) void finalize_kernel(const float* __restrict__ h,
                                                       const float* __restrict__ dinv,
                                                       const float* __restrict__ b,
                                                       float* __restrict__ agg, int N) {
    long long i = (long long)blockIdx.x * 256 + threadIdx.x;
    if (i >= (long long)N * H) return;
    int node = (int)(i >> 5);
    int f = (int)(i & 31);
    float di = dinv[node];
    float v = agg[i] + h[i] * di * di + b[f];
    agg[i] = fmaxf(v, 0.f);
}

// ---------- pooling + head ----------
__global__ __launch_bounds__(256) void pool_kernel(const float* __restrict__ h,
                                                   float* __restrict__ g, long long total) {
    __shared__ float s[256];
    int tid = threadIdx.x;
    float acc = 0.f;
    for (long long i = (long long)blockIdx.x * 256 + tid; i < total;
         i += (long long)gridDim.x * 256)
        acc += h[i];
    s[tid] = acc;
    __syncthreads();
    // strides are multiples of 32 so each slot keeps its feature index f = tid&31
    for (int off = 128; off >= 32; off >>= 1) {
        if (tid < off) s[tid] += s[tid + off];
        __syncthreads();
    }
    if (tid < 32) atomicAdd(&g[tid], s[tid]);
}

__global__ __launch_bounds__(64) void head_kernel(const float* __restrict__ g,
                                                  const float* __restrict__ Wl1,
                                                  const float* __restrict__ bl1,
                                                  const float* __restrict__ Wl2,
                                                  const float* __restrict__ bl2,
                                                  float* __restrict__ out) {
    __shared__ float t[16];
    int tid = threadIdx.x;
    if (tid < 16) {
        float s = bl1[tid];
        #pragma unroll
        for (int k = 0; k < 32; k++) s += g[k] * Wl1[k * 16 + tid];
        t[tid] = fmaxf(s, 0.f);
    }
    __syncthreads();
    if (tid < 3) {
        float s = bl2[tid];
        #pragma unroll
        for (int k = 0; k < 16; k++) s += t[k] * Wl2[k * 3 + tid];
        out[tid] = s;
    }
}

extern "C" void kernel_launch(void* const* d_in, const int* in_sizes, int n_in,
                              void* d_out, int out_size, void* d_ws, size_t ws_size,
                              hipStream_t stream) {
    const float* x   = (const float*)d_in[0];
    const int*   ei  = (const int*)d_in[1];
    const float* W1  = (const float*)d_in[2];
    const float* b1  = (const float*)d_in[3];
    const float* W2  = (const float*)d_in[4];
    const float* b2  = (const float*)d_in[5];
    const float* W3  = (const float*)d_in[6];
    const float* b3  = (const float*)d_in[7];
    const float* W4  = (const float*)d_in[8];
    const float* b4  = (const float*)d_in[9];
    const float* Wl1 = (const float*)d_in[10];
    const float* bl1 = (const float*)d_in[11];
    const float* Wl2 = (const float*)d_in[12];
    const float* bl2 = (const float*)d_in[13];
    float* out = (float*)d_out;

    const int N = in_sizes[0] / F_IN;
    const int E = in_sizes[1] / 2;

    // workspace layout
    char* ws = (char*)d_ws;
    size_t off = 0;
    auto alloc = [&](size_t bytes) {
        char* p = ws + off;
        off += (bytes + 255) & ~(size_t)255;
        return p;
    };
    float* dinv = (float*)alloc((size_t)N * 4);          // deg then dinv in place
    float* norm = (float*)alloc((size_t)E * 4);
    float* bufA = (float*)alloc((size_t)N * H * 4);      // dense output h
    float* bufB = (float*)alloc((size_t)N * H * 4);      // agg / layer output
    float* g    = (float*)alloc(128);

    const int TB = 256;
    const int gE   = (E + TB - 1) / TB;
    const int gN   = (N + TB - 1) / TB;
    const int gNode = (N + 7) / 8;
    const long long totNH = (long long)N * H;
    const int gNH  = (int)((totNH + TB - 1) / TB);
    const int gEH  = (int)(((long long)E * H + TB - 1) / TB);

    // degrees + norms (once per call)
    hipMemsetAsync(dinv, 0, (size_t)N * 4, stream);
    deg_kernel<<<gE, TB, 0, stream>>>(ei, dinv, E);
    dinv_kernel<<<gN, TB, 0, stream>>>(dinv, N);
    norm_kernel<<<gE, TB, 0, stream>>>(ei, dinv, norm, E);

    const float* layer_in = x;
    const float* Ws[4] = {W1, W2, W3, W4};
    const float* bs[4] = {b1, b2, b3, b4};
    for (int l = 0; l < 4; l++) {
        if (l == 0)
            gemm1_kernel<<<gNode, TB, 0, stream>>>(layer_in, Ws[l], bufA, N);
        else
            gemmh_kernel<<<gNode, TB, 0, stream>>>(layer_in, Ws[l], bufA, N);
        hipMemsetAsync(bufB, 0, (size_t)totNH * 4, stream);
        agg_kernel<<<gEH, TB, 0, stream>>>(ei, norm, bufA, bufB, E);
        finalize_kernel<<<gNH, TB, 0, stream>>>(bufA, dinv, bs[l], bufB, N);
        layer_in = bufB;   // next layer reads bufB; bufA freely overwritten
    }

    hipMemsetAsync(g, 0, 128, stream);
    pool_kernel<<<1024, TB, 0, stream>>>(bufB, g, totNH);
    head_kernel<<<1, 64, 0, stream>>>(g, Wl1, bl1, Wl2, bl2, out);
}

// Round 2
// 1045.317 us; speedup vs baseline: 1.4292x; 1.4292x over previous
//
#include <hip/hip_runtime.h>

#define F_IN 61
#define H 32

// ---------- CSR build ----------
__global__ __launch_bounds__(256) void deg_kernel(const int* __restrict__ ei,
                                                  int* __restrict__ deg, int E) {
    int e = blockIdx.x * 256 + threadIdx.x;
    if (e < E) atomicAdd(&deg[ei[E + e]], 1);
}

__global__ __launch_bounds__(256) void dinv_kernel(const int* __restrict__ deg,
                                                   float* __restrict__ dinv, int N) {
    int i = blockIdx.x * 256 + threadIdx.x;
    if (i < N) dinv[i] = rsqrtf((float)deg[i] + 1.0f);   // +1 self-loop
}

// exclusive scan, 3 kernels, 256 elements per block
__global__ __launch_bounds__(256) void scan1_kernel(const int* __restrict__ deg,
                                                    int* __restrict__ scanned,
                                                    int* __restrict__ btot, int N) {
    __shared__ int s[256];
    int tid = threadIdx.x;
    int i = blockIdx.x * 256 + tid;
    int v = (i < N) ? deg[i] : 0;
    s[tid] = v;
    __syncthreads();
    for (int off = 1; off < 256; off <<= 1) {
        int t = (tid >= off) ? s[tid - off] : 0;
        __syncthreads();
        s[tid] += t;
        __syncthreads();
    }
    if (i < N) scanned[i] = s[tid] - v;          // exclusive within block
    if (tid == 255) btot[blockIdx.x] = s[255];   // block total
}

__global__ __launch_bounds__(1024) void scan2_kernel(int* __restrict__ btot, int nB) {
    __shared__ int s[1024];
    int tid = threadIdx.x;
    int v = (tid < nB) ? btot[tid] : 0;
    s[tid] = v;
    __syncthreads();
    for (int off = 1; off < 1024; off <<= 1) {
        int t = (tid >= off) ? s[tid - off] : 0;
        __syncthreads();
        s[tid] += t;
        __syncthreads();
    }
    if (tid < nB) btot[tid] = s[tid] - v;        // exclusive over blocks
}

__global__ __launch_bounds__(256) void scan3_kernel(const int* __restrict__ scanned,
                                                    const int* __restrict__ btot,
                                                    int* __restrict__ row_start, int N, int E) {
    int i = blockIdx.x * 256 + threadIdx.x;
    if (i < N) row_start[i] = scanned[i] + btot[blockIdx.x];
    if (i == 0) row_start[N] = E;
}

__global__ __launch_bounds__(256) void scatter_kernel(const int* __restrict__ ei,
                                                      const int* __restrict__ row_start,
                                                      int* __restrict__ cursor,
                                                      int* __restrict__ src_sorted, int E) {
    int e = blockIdx.x * 256 + threadIdx.x;
    if (e < E) {
        int d = ei[E + e];
        int pos = row_start[d] + atomicAdd(&cursor[d], 1);
        src_sorted[pos] = ei[e];
    }
}

// ---------- dense layers ----------
__global__ __launch_bounds__(256) void gemm1_kernel(const float* __restrict__ x,
                                                    const float* __restrict__ W,
                                                    float* __restrict__ h, int N) {
    __shared__ float Ws[F_IN * H];
    int tid = threadIdx.x;
    for (int i = tid; i < F_IN * H; i += 256) Ws[i] = W[i];
    __syncthreads();
    int node = blockIdx.x * 8 + (tid >> 5);
    int f = tid & 31;
    if (node < N) {
        const float* xr = x + (long long)node * F_IN;
        float s = 0.f;
        #pragma unroll
        for (int k = 0; k < F_IN; k++) s += xr[k] * Ws[k * H + f];
        h[(long long)node * H + f] = s;
    }
}

__global__ __launch_bounds__(256) void gemmh_kernel(const float* __restrict__ x,
                                                    const float* __restrict__ W,
                                                    float* __restrict__ h, int N) {
    __shared__ float Ws[H * H];
    int tid = threadIdx.x;
    for (int i = tid; i < H * H; i += 256) Ws[i] = W[i];
    __syncthreads();
    int node = blockIdx.x * 8 + (tid >> 5);
    int f = tid & 31;
    if (node < N) {
        const float* xr = x + (long long)node * H;
        float s = 0.f;
        #pragma unroll
        for (int k = 0; k < H; k++) s += xr[k] * Ws[k * H + f];
        h[(long long)node * H + f] = s;
    }
}

// ---------- pull-mode aggregation: 32 lanes per dst node, no atomics ----------
// out[d][f] = relu( h[d][f]*dinv[d]^2 + b[f] + sum_e h[src][f]*dinv[src]*dinv[d] )
__global__ __launch_bounds__(256) void agg_csr_kernel(const int* __restrict__ row_start,
                                                      const int* __restrict__ src_sorted,
                                                      const float* __restrict__ dinv,
                                                      const float* __restrict__ h,
                                                      const float* __restrict__ b,
                                                      float* __restrict__ out, int N) {
    int tid = threadIdx.x;
    int node = blockIdx.x * 8 + (tid >> 5);
    int f = tid & 31;
    if (node >= N) return;
    float di = dinv[node];
    float acc = h[(long long)node * H + f] * di * di + b[f];
    int e0 = row_start[node], e1 = row_start[node + 1];
    for (int e = e0; e < e1; e++) {
        int s = src_sorted[e];
        acc += h[(long long)s * H + f] * (dinv[s] * di);
    }
    out[(long long)node * H + f] = fmaxf(acc, 0.f);
}

// ---------- pooling + head ----------
__global__ __launch_bounds__(256) void pool_kernel(const float* __restrict__ h,
                                                   float* __restrict__ g, long long total) {
    __shared__ float s[256];
    int tid = threadIdx.x;
    float acc = 0.f;
    for (long long i = (long long)blockIdx.x * 256 + tid; i < total;
         i += (long long)gridDim.x * 256)
        acc += h[i];
    s[tid] = acc;
    __syncthreads();
    for (int off = 128; off >= 32; off >>= 1) {
        if (tid < off) s[tid] += s[tid + off];
        __syncthreads();
    }
    if (tid < 32) atomicAdd(&g[tid], s[tid]);
}

__global__ __launch_bounds__(64) void head_kernel(const float* __restrict__ g,
                                                  const float* __restrict__ Wl1,
                                                  const float* __restrict__ bl1,
                                                  const float* __restrict__ Wl2,
                                                  const float* __restrict__ bl2,
                                                  float* __restrict__ out) {
    __shared__ float t[16];
    int tid = threadIdx.x;
    if (tid < 16) {
        float s = bl1[tid];
        #pragma unroll
        for (int k = 0; k < 32; k++) s += g[k] * Wl1[k * 16 + tid];
        t[tid] = fmaxf(s, 0.f);
    }
    __syncthreads();
    if (tid < 3) {
        float s = bl2[tid];
        #pragma unroll
        for (int k = 0; k < 16; k++) s += t[k] * Wl2[k * 3 + tid];
        out[tid] = s;
    }
}

extern "C" void kernel_launch(void* const* d_in, const int* in_sizes, int n_in,
                              void* d_out, int out_size, void* d_ws, size_t ws_size,
                              hipStream_t stream) {
    const float* x   = (const float*)d_in[0];
    const int*   ei  = (const int*)d_in[1];
    const float* W1  = (const float*)d_in[2];
    const float* b1  = (const float*)d_in[3];
    const float* W2  = (const float*)d_in[4];
    const float* b2  = (const float*)d_in[5];
    const float* W3  = (const float*)d_in[6];
    const float* b3  = (const float*)d_in[7];
    const float* W4  = (const float*)d_in[8];
    const float* b4  = (const float*)d_in[9];
    const float* Wl1 = (const float*)d_in[10];
    const float* bl1 = (const float*)d_in[11];
    const float* Wl2 = (const float*)d_in[12];
    const float* bl2 = (const float*)d_in[13];
    float* out = (float*)d_out;

    const int N = in_sizes[0] / F_IN;
    const int E = in_sizes[1] / 2;

    char* ws = (char*)d_ws;
    size_t off = 0;
    auto alloc = [&](size_t bytes) {
        char* p = ws + off;
        off += (bytes + 255) & ~(size_t)255;
        return p;
    };
    int*   deg        = (int*)alloc((size_t)N * 4);
    float* dinv       = (float*)alloc((size_t)N * 4);
    int*   scanned    = (int*)alloc((size_t)N * 4);
    int*   btot       = (int*)alloc(((size_t)N / 256 + 2) * 4);
    int*   row_start  = (int*)alloc((size_t)(N + 1) * 4);
    int*   cursor     = (int*)alloc((size_t)N * 4);
    int*   src_sorted = (int*)alloc((size_t)E * 4);
    float* bufA       = (float*)alloc((size_t)N * H * 4);
    float* bufB       = (float*)alloc((size_t)N * H * 4);
    float* g          = (float*)alloc(128);

    const int TB = 256;
    const int gE  = (E + TB - 1) / TB;
    const int gN  = (N + TB - 1) / TB;      // also the scan block count (<=1024 for N<=262144)
    const int gNode = (N + 7) / 8;
    const long long totNH = (long long)N * H;

    // CSR build (once per call)
    hipMemsetAsync(deg, 0, (size_t)N * 4, stream);
    hipMemsetAsync(cursor, 0, (size_t)N * 4, stream);
    deg_kernel<<<gE, TB, 0, stream>>>(ei, deg, E);
    dinv_kernel<<<gN, TB, 0, stream>>>(deg, dinv, N);
    scan1_kernel<<<gN, TB, 0, stream>>>(deg, scanned, btot, N);
    scan2_kernel<<<1, 1024, 0, stream>>>(btot, gN);
    scan3_kernel<<<gN, TB, 0, stream>>>(scanned, btot, row_start, N, E);
    scatter_kernel<<<gE, TB, 0, stream>>>(ei, row_start, cursor, src_sorted, E);

    // 4 GCN layers: dense transform into bufA, pull-aggregate into bufB
    const float* layer_in = x;
    const float* Wp[4] = {W1, W2, W3, W4};
    const float* bp[4] = {b1, b2, b3, b4};
    for (int l = 0; l < 4; l++) {
        if (l == 0)
            gemm1_kernel<<<gNode, TB, 0, stream>>>(layer_in, Wp[l], bufA, N);
        else
            gemmh_kernel<<<gNode, TB, 0, stream>>>(layer_in, Wp[l], bufA, N);
        agg_csr_kernel<<<gNode, TB, 0, stream>>>(row_start, src_sorted, dinv,
                                                 bufA, bp[l], bufB, N);
        layer_in = bufB;
    }

    hipMemsetAsync(g, 0, 128, stream);
    pool_kernel<<<1024, TB, 0, stream>>>(bufB, g, totNH);
    head_kernel<<<1, 64, 0, stream>>>(g, Wl1, bl1, Wl2, bl2, out);
}

// Round 3
// 900.896 us; speedup vs baseline: 1.6583x; 1.1603x over previous
//
#include <hip/hip_runtime.h>

#define F_IN 61
#define H 32
#define BSHIFT 6                 // bucket = dst >> 6  (64 dst nodes per bucket)

// ---------- degree / dinv ----------
__global__ __launch_bounds__(256) void deg_kernel(const int* __restrict__ ei,
                                                  int* __restrict__ deg, int E) {
    int e = blockIdx.x * 256 + threadIdx.x;
    if (e < E) atomicAdd(&deg[ei[E + e]], 1);
}

__global__ __launch_bounds__(256) void dinv_kernel(const int* __restrict__ deg,
                                                   float* __restrict__ dinv, int N) {
    int i = blockIdx.x * 256 + threadIdx.x;
    if (i < N) dinv[i] = rsqrtf((float)deg[i] + 1.0f);   // +1 self-loop
}

// ---------- exclusive scan over deg (3 kernels) ----------
__global__ __launch_bounds__(256) void scan1_kernel(const int* __restrict__ deg,
                                                    int* __restrict__ scanned,
                                                    int* __restrict__ btot, int N) {
    __shared__ int s[256];
    int tid = threadIdx.x;
    int i = blockIdx.x * 256 + tid;
    int v = (i < N) ? deg[i] : 0;
    s[tid] = v;
    __syncthreads();
    for (int off = 1; off < 256; off <<= 1) {
        int t = (tid >= off) ? s[tid - off] : 0;
        __syncthreads();
        s[tid] += t;
        __syncthreads();
    }
    if (i < N) scanned[i] = s[tid] - v;
    if (tid == 255) btot[blockIdx.x] = s[255];
}

__global__ __launch_bounds__(1024) void scan2_kernel(int* __restrict__ btot, int nB) {
    __shared__ int s[1024];
    int tid = threadIdx.x;
    int v = (tid < nB) ? btot[tid] : 0;
    s[tid] = v;
    __syncthreads();
    for (int off = 1; off < 1024; off <<= 1) {
        int t = (tid >= off) ? s[tid - off] : 0;
        __syncthreads();
        s[tid] += t;
        __syncthreads();
    }
    if (tid < nB) btot[tid] = s[tid] - v;
}

__global__ __launch_bounds__(256) void scan3_kernel(const int* __restrict__ scanned,
                                                    const int* __restrict__ btot,
                                                    int* __restrict__ row_start, int N, int E) {
    int i = blockIdx.x * 256 + threadIdx.x;
    if (i < N) row_start[i] = scanned[i] + btot[blockIdx.x];
    if (i == 0) row_start[N] = E;
}

// ---------- binned counting sort ----------
__global__ __launch_bounds__(256) void bcur_init_kernel(const int* __restrict__ row_start,
                                                        int* __restrict__ bcur, int K, int N) {
    int b = blockIdx.x * 256 + threadIdx.x;
    if (b < K) {
        int base = b << BSHIFT;
        bcur[b] = row_start[base < N ? base : N];
    }
}

// Pass A: scatter edges into bucket regions (bucket = CSR segment range of its
// 64-node dst slice, so positions are final-CSR-region-local). Only K hot
// write lines -> ~1x write amplification. Payload: (src<<6)|(dst&63).
__global__ __launch_bounds__(256) void partA_kernel(const int* __restrict__ ei,
                                                    int* __restrict__ bcur,
                                                    int* __restrict__ tmp, int E) {
    int e = blockIdx.x * 256 + threadIdx.x;
    if (e < E) {
        int s = ei[e];
        int d = ei[E + e];
        int p = atomicAdd(&bcur[d >> BSHIFT], 1);
        tmp[p] = (s << BSHIFT) | (d & 63);
    }
}

// Pass B: one block per bucket; per-node cursors in LDS; writes confined to a
// ~4KB CSR region. Also emits norm_sorted = dinv[src]*dinv[dst].
__global__ __launch_bounds__(256) void partB_kernel(const int* __restrict__ row_start,
                                                    const int* __restrict__ tmp,
                                                    const float* __restrict__ dinv,
                                                    int* __restrict__ src_sorted,
                                                    float* __restrict__ norm_sorted, int N) {
    __shared__ int lcur[64];
    __shared__ float ldinv[64];
    int b = blockIdx.x;
    int base = b << BSHIFT;
    int tid = threadIdx.x;
    int nn = N - base; if (nn > 64) nn = 64;
    if (tid < nn) {
        lcur[tid] = row_start[base + tid];
        ldinv[tid] = dinv[base + tid];
    }
    __syncthreads();
    int e0 = row_start[base];
    int e1 = row_start[(base + 64 < N) ? base + 64 : N];
    for (int i = e0 + tid; i < e1; i += 256) {
        int v = tmp[i];
        int dl = v & 63;
        int s = v >> BSHIFT;
        int pos = atomicAdd(&lcur[dl], 1);
        src_sorted[pos] = s;
        norm_sorted[pos] = dinv[s] * ldinv[dl];
    }
}

// ---------- dense layers ----------
__global__ __launch_bounds__(256) void gemm1_kernel(const float* __restrict__ x,
                                                    const float* __restrict__ W,
                                                    float* __restrict__ h, int N) {
    __shared__ float Ws[F_IN * H];
    int tid = threadIdx.x;
    for (int i = tid; i < F_IN * H; i += 256) Ws[i] = W[i];
    __syncthreads();
    int node = blockIdx.x * 8 + (tid >> 5);
    int f = tid & 31;
    if (node < N) {
        const float* xr = x + (long long)node * F_IN;
        float s = 0.f;
        #pragma unroll
        for (int k = 0; k < F_IN; k++) s += xr[k] * Ws[k * H + f];
        h[(long long)node * H + f] = s;
    }
}

__global__ __launch_bounds__(256) void gemmh_kernel(const float* __restrict__ x,
                                                    const float* __restrict__ W,
                                                    float* __restrict__ h, int N) {
    __shared__ float Ws[H * H];
    int tid = threadIdx.x;
    for (int i = tid; i < H * H; i += 256) Ws[i] = W[i];
    __syncthreads();
    int node = blockIdx.x * 8 + (tid >> 5);
    int f = tid & 31;
    if (node < N) {
        const float* xr = x + (long long)node * H;
        float s = 0.f;
        #pragma unroll
        for (int k = 0; k < H; k++) s += xr[k] * Ws[k * H + f];
        h[(long long)node * H + f] = s;
    }
}

// ---------- pull-mode aggregation, 4-edge unrolled ----------
__global__ __launch_bounds__(256) void agg_csr_kernel(const int* __restrict__ row_start,
                                                      const int* __restrict__ src_sorted,
                                                      const float* __restrict__ norm_sorted,
                                                      const float* __restrict__ dinv,
                                                      const float* __restrict__ h,
                                                      const float* __restrict__ b,
                                                      float* __restrict__ out, int N) {
    int tid = threadIdx.x;
    int node = blockIdx.x * 8 + (tid >> 5);
    int f = tid & 31;
    if (node >= N) return;
    float di = dinv[node];
    float acc = h[(long long)node * H + f] * di * di + b[f];
    int e0 = row_start[node], e1 = row_start[node + 1];
    int e = e0;
    for (; e + 4 <= e1; e += 4) {
        int s0 = src_sorted[e];
        int s1 = src_sorted[e + 1];
        int s2 = src_sorted[e + 2];
        int s3 = src_sorted[e + 3];
        float w0 = norm_sorted[e];
        float w1 = norm_sorted[e + 1];
        float w2 = norm_sorted[e + 2];
        float w3 = norm_sorted[e + 3];
        float h0 = h[(long long)s0 * H + f];
        float h1 = h[(long long)s1 * H + f];
        float h2 = h[(long long)s2 * H + f];
        float h3 = h[(long long)s3 * H + f];
        acc += h0 * w0 + h1 * w1 + h2 * w2 + h3 * w3;
    }
    for (; e < e1; e++)
        acc += h[(long long)src_sorted[e] * H + f] * norm_sorted[e];
    out[(long long)node * H + f] = fmaxf(acc, 0.f);
}

// ---------- pooling + head ----------
__global__ __launch_bounds__(256) void pool_kernel(const float* __restrict__ h,
                                                   float* __restrict__ g, long long total) {
    __shared__ float s[256];
    int tid = threadIdx.x;
    float acc = 0.f;
    for (long long i = (long long)blockIdx.x * 256 + tid; i < total;
         i += (long long)gridDim.x * 256)
        acc += h[i];
    s[tid] = acc;
    __syncthreads();
    for (int off = 128; off >= 32; off >>= 1) {
        if (tid < off) s[tid] += s[tid + off];
        __syncthreads();
    }
    if (tid < 32) atomicAdd(&g[tid], s[tid]);
}

__global__ __launch_bounds__(64) void head_kernel(const float* __restrict__ g,
                                                  const float* __restrict__ Wl1,
                                                  const float* __restrict__ bl1,
                                                  const float* __restrict__ Wl2,
                                                  const float* __restrict__ bl2,
                                                  float* __restrict__ out) {
    __shared__ float t[16];
    int tid = threadIdx.x;
    if (tid < 16) {
        float s = bl1[tid];
        #pragma unroll
        for (int k = 0; k < 32; k++) s += g[k] * Wl1[k * 16 + tid];
        t[tid] = fmaxf(s, 0.f);
    }
    __syncthreads();
    if (tid < 3) {
        float s = bl2[tid];
        #pragma unroll
        for (int k = 0; k < 16; k++) s += t[k] * Wl2[k * 3 + tid];
        out[tid] = s;
    }
}

extern "C" void kernel_launch(void* const* d_in, const int* in_sizes, int n_in,
                              void* d_out, int out_size, void* d_ws, size_t ws_size,
                              hipStream_t stream) {
    const float* x   = (const float*)d_in[0];
    const int*   ei  = (const int*)d_in[1];
    const float* W1  = (const float*)d_in[2];
    const float* b1  = (const float*)d_in[3];
    const float* W2  = (const float*)d_in[4];
    const float* b2  = (const float*)d_in[5];
    const float* W3  = (const float*)d_in[6];
    const float* b3  = (const float*)d_in[7];
    const float* W4  = (const float*)d_in[8];
    const float* b4  = (const float*)d_in[9];
    const float* Wl1 = (const float*)d_in[10];
    const float* bl1 = (const float*)d_in[11];
    const float* Wl2 = (const float*)d_in[12];
    const float* bl2 = (const float*)d_in[13];
    float* out = (float*)d_out;

    const int N = in_sizes[0] / F_IN;
    const int E = in_sizes[1] / 2;
    const int K = (N + 63) >> BSHIFT;    // buckets

    char* ws = (char*)d_ws;
    size_t off = 0;
    auto alloc = [&](size_t bytes) {
        char* p = ws + off;
        off += (bytes + 255) & ~(size_t)255;
        return p;
    };
    int*   deg         = (int*)alloc((size_t)N * 4);
    float* dinv        = (float*)alloc((size_t)N * 4);
    int*   scanned     = (int*)alloc((size_t)N * 4);
    int*   btot        = (int*)alloc(((size_t)N / 256 + 2) * 4);
    int*   row_start   = (int*)alloc((size_t)(N + 1) * 4);
    int*   bcur        = (int*)alloc((size_t)(K + 1) * 4);
    int*   src_sorted  = (int*)alloc((size_t)E * 4);
    float* norm_sorted = (float*)alloc((size_t)E * 4);
    float* bufA        = (float*)alloc((size_t)N * H * 4);   // also aliased as tmp (E*4 <= N*H*4)
    float* bufB        = (float*)alloc((size_t)N * H * 4);
    float* g           = (float*)alloc(128);
    int*   tmp         = (int*)bufA;     // CSR-build scratch, dead before gemm1 writes bufA

    const int TB = 256;
    const int gE  = (E + TB - 1) / TB;
    const int gN  = (N + TB - 1) / TB;   // scan block count (<=1024 for N<=262144)
    const int gK  = (K + TB - 1) / TB;
    const int gNode = (N + 7) / 8;
    const long long totNH = (long long)N * H;

    // ---- CSR build ----
    hipMemsetAsync(deg, 0, (size_t)N * 4, stream);
    deg_kernel<<<gE, TB, 0, stream>>>(ei, deg, E);
    dinv_kernel<<<gN, TB, 0, stream>>>(deg, dinv, N);
    scan1_kernel<<<gN, TB, 0, stream>>>(deg, scanned, btot, N);
    scan2_kernel<<<1, 1024, 0, stream>>>(btot, gN);
    scan3_kernel<<<gN, TB, 0, stream>>>(scanned, btot, row_start, N, E);
    bcur_init_kernel<<<gK, TB, 0, stream>>>(row_start, bcur, K, N);
    partA_kernel<<<gE, TB, 0, stream>>>(ei, bcur, tmp, E);
    partB_kernel<<<K, TB, 0, stream>>>(row_start, tmp, dinv, src_sorted, norm_sorted, N);

    // ---- 4 GCN layers ----
    const float* layer_in = x;
    const float* Wp[4] = {W1, W2, W3, W4};
    const float* bp[4] = {b1, b2, b3, b4};
    for (int l = 0; l < 4; l++) {
        if (l == 0)
            gemm1_kernel<<<gNode, TB, 0, stream>>>(layer_in, Wp[l], bufA, N);
        else
            gemmh_kernel<<<gNode, TB, 0, stream>>>(layer_in, Wp[l], bufA, N);
        agg_csr_kernel<<<gNode, TB, 0, stream>>>(row_start, src_sorted, norm_sorted,
                                                 dinv, bufA, bp[l], bufB, N);
        layer_in = bufB;
    }

    // ---- pool + head ----
    hipMemsetAsync(g, 0, 128, stream);
    pool_kernel<<<1024, TB, 0, stream>>>(bufB, g, totNH);
    head_kernel<<<1, 64, 0, stream>>>(g, Wl1, bl1, Wl2, bl2, out);
}

// Round 4
// 654.941 us; speedup vs baseline: 2.2811x; 1.3755x over previous
//
#include <hip/hip_runtime.h>

#define F_IN 61
#define H 32
#define NSLICE 8        // dst slices == XCD count; blockIdx&7 round-robins XCDs
#define MCHUNK 256      // edge chunks per slice in scatter

// ---------- degree / dinv ----------
__global__ __launch_bounds__(256) void deg_kernel(const int* __restrict__ ei,
                                                  int* __restrict__ deg, int E) {
    int e = blockIdx.x * 256 + threadIdx.x;
    if (e < E) atomicAdd(&deg[ei[E + e]], 1);
}

__global__ __launch_bounds__(256) void dinv_kernel(const int* __restrict__ deg,
                                                   float* __restrict__ dinv, int N) {
    int i = blockIdx.x * 256 + threadIdx.x;
    if (i < N) dinv[i] = rsqrtf((float)deg[i] + 1.0f);   // +1 self-loop
}

// ---------- exclusive scan over deg (3 kernels) ----------
__global__ __launch_bounds__(256) void scan1_kernel(const int* __restrict__ deg,
                                                    int* __restrict__ scanned,
                                                    int* __restrict__ btot, int N) {
    __shared__ int s[256];
    int tid = threadIdx.x;
    int i = blockIdx.x * 256 + tid;
    int v = (i < N) ? deg[i] : 0;
    s[tid] = v;
    __syncthreads();
    for (int off = 1; off < 256; off <<= 1) {
        int t = (tid >= off) ? s[tid - off] : 0;
        __syncthreads();
        s[tid] += t;
        __syncthreads();
    }
    if (i < N) scanned[i] = s[tid] - v;
    if (tid == 255) btot[blockIdx.x] = s[255];
}

__global__ __launch_bounds__(1024) void scan2_kernel(int* __restrict__ btot, int nB) {
    __shared__ int s[1024];
    int tid = threadIdx.x;
    int v = (tid < nB) ? btot[tid] : 0;
    s[tid] = v;
    __syncthreads();
    for (int off = 1; off < 1024; off <<= 1) {
        int t = (tid >= off) ? s[tid - off] : 0;
        __syncthreads();
        s[tid] += t;
        __syncthreads();
    }
    if (tid < nB) btot[tid] = s[tid] - v;
}

__global__ __launch_bounds__(256) void scan3_kernel(const int* __restrict__ scanned,
                                                    const int* __restrict__ btot,
                                                    int* __restrict__ row_start, int N, int E) {
    int i = blockIdx.x * 256 + threadIdx.x;
    if (i < N) row_start[i] = scanned[i] + btot[blockIdx.x];
    if (i == 0) row_start[N] = E;
}

// ---------- XCD-sliced scatter ----------
// slice = blockIdx&7 maps round-robin onto the 8 XCDs; each slice only writes
// the contiguous CSR window of its dst range -> window (~2.4MB) stays in that
// XCD's L2, lines fill completely before writeback (~1x write amplification).
// Per-node cursors: 150k counters, ~16-deep atomic chains (low contention).
__global__ __launch_bounds__(256) void scatter_kernel(const int* __restrict__ ei,
                                                      const int* __restrict__ row_start,
                                                      int* __restrict__ cursor,
                                                      const float* __restrict__ dinv,
                                                      int* __restrict__ src_sorted,
                                                      float* __restrict__ norm_sorted,
                                                      int E, int N) {
    int slice = blockIdx.x & (NSLICE - 1);
    int j = blockIdx.x >> 3;
    int lo = (int)((long long)slice * N / NSLICE);
    int hi = (int)((long long)(slice + 1) * N / NSLICE);
    int e0 = (int)((long long)j * E / MCHUNK);
    int e1 = (int)((long long)(j + 1) * E / MCHUNK);
    for (int e = e0 + threadIdx.x; e < e1; e += 256) {
        int d = ei[E + e];
        if (d >= lo && d < hi) {
            int s = ei[e];
            int pos = row_start[d] + atomicAdd(&cursor[d], 1);
            src_sorted[pos] = s;
            norm_sorted[pos] = dinv[s] * dinv[d];
        }
    }
}

// ---------- layer 1 dense: x(N x 61) @ W1 -> h1 ----------
__global__ __launch_bounds__(256) void gemm1_kernel(const float* __restrict__ x,
                                                    const float* __restrict__ W,
                                                    float* __restrict__ h, int N) {
    __shared__ float Ws[F_IN * H];
    __shared__ float xs[8 * F_IN];
    int tid = threadIdx.x;
    for (int i = tid; i < F_IN * H; i += 256) Ws[i] = W[i];
    int nb = blockIdx.x * 8;
    int navail = N - nb; if (navail > 8) navail = 8;
    const float* xb = x + (long long)nb * F_IN;
    for (int i = tid; i < navail * F_IN; i += 256) xs[i] = xb[i];
    __syncthreads();
    int nl = tid >> 5, f = tid & 31;
    int node = nb + nl;
    if (node < N) {
        float s = 0.f;
        #pragma unroll
        for (int k = 0; k < F_IN; k++) s += xs[nl * F_IN + k] * Ws[k * H + f];
        h[(long long)node * H + f] = s;
    }
}

// ---------- fused: X = relu(agg(h)+b); hout = X @ Wn ----------
// 8 nodes/block, 32 lanes per node. agg row -> LDS tile -> block-local GEMM.
__global__ __launch_bounds__(256) void agg_gemm_kernel(const int* __restrict__ row_start,
                                                       const int* __restrict__ src_sorted,
                                                       const float* __restrict__ norm_sorted,
                                                       const float* __restrict__ dinv,
                                                       const float* __restrict__ h,
                                                       const float* __restrict__ b,
                                                       const float* __restrict__ Wn,
                                                       float* __restrict__ hout, int N) {
    __shared__ float Ws[H * H];
    __shared__ float t[8 * H];
    int tid = threadIdx.x;
    for (int i = tid; i < H * H; i += 256) Ws[i] = Wn[i];
    int nl = tid >> 5, f = tid & 31;
    int node = blockIdx.x * 8 + nl;
    if (node < N) {
        float di = dinv[node];
        float acc = h[(long long)node * H + f] * di * di + b[f];
        int e0 = row_start[node], e1 = row_start[node + 1];
        int e = e0;
        for (; e + 4 <= e1; e += 4) {
            int s0 = src_sorted[e];
            int s1 = src_sorted[e + 1];
            int s2 = src_sorted[e + 2];
            int s3 = src_sorted[e + 3];
            float w0 = norm_sorted[e];
            float w1 = norm_sorted[e + 1];
            float w2 = norm_sorted[e + 2];
            float w3 = norm_sorted[e + 3];
            float h0 = h[(long long)s0 * H + f];
            float h1 = h[(long long)s1 * H + f];
            float h2 = h[(long long)s2 * H + f];
            float h3 = h[(long long)s3 * H + f];
            acc += h0 * w0 + h1 * w1 + h2 * w2 + h3 * w3;
        }
        for (; e < e1; e++)
            acc += h[(long long)src_sorted[e] * H + f] * norm_sorted[e];
        t[nl * H + f] = fmaxf(acc, 0.f);
    }
    __syncthreads();
    if (node < N) {
        float s = 0.f;
        #pragma unroll
        for (int k = 0; k < H; k++) s += t[nl * H + k] * Ws[k * H + f];
        hout[(long long)node * H + f] = s;
    }
}

// ---------- final layer: X5 = relu(agg(h4)+b4); pool into 64 spread copies ----------
__global__ __launch_bounds__(256) void agg_pool_kernel(const int* __restrict__ row_start,
                                                       const int* __restrict__ src_sorted,
                                                       const float* __restrict__ norm_sorted,
                                                       const float* __restrict__ dinv,
                                                       const float* __restrict__ h,
                                                       const float* __restrict__ b,
                                                       float* __restrict__ gs, int N) {
    __shared__ float t[8 * H];
    int tid = threadIdx.x;
    int nl = tid >> 5, f = tid & 31;
    int node = blockIdx.x * 8 + nl;
    float val = 0.f;
    if (node < N) {
        float di = dinv[node];
        float acc = h[(long long)node * H + f] * di * di + b[f];
        int e0 = row_start[node], e1 = row_start[node + 1];
        int e = e0;
        for (; e + 4 <= e1; e += 4) {
            int s0 = src_sorted[e];
            int s1 = src_sorted[e + 1];
            int s2 = src_sorted[e + 2];
            int s3 = src_sorted[e + 3];
            float w0 = norm_sorted[e];
            float w1 = norm_sorted[e + 1];
            float w2 = norm_sorted[e + 2];
            float w3 = norm_sorted[e + 3];
            acc += h[(long long)s0 * H + f] * w0 + h[(long long)s1 * H + f] * w1
                 + h[(long long)s2 * H + f] * w2 + h[(long long)s3 * H + f] * w3;
        }
        for (; e < e1; e++)
            acc += h[(long long)src_sorted[e] * H + f] * norm_sorted[e];
        val = fmaxf(acc, 0.f);
    }
    t[nl * H + f] = val;
    __syncthreads();
    if (tid < H) {
        float s = 0.f;
        #pragma unroll
        for (int r = 0; r < 8; r++) s += t[r * H + tid];
        atomicAdd(&gs[(blockIdx.x & 63) * H + tid], s);
    }
}

// ---------- head: reduce 64 pool copies, 32->16 relu, 16->3 ----------
__global__ __launch_bounds__(64) void head_kernel(const float* __restrict__ gs,
                                                  const float* __restrict__ Wl1,
                                                  const float* __restrict__ bl1,
                                                  const float* __restrict__ Wl2,
                                                  const float* __restrict__ bl2,
                                                  float* __restrict__ out) {
    __shared__ float gg[H];
    __shared__ float t[16];
    int tid = threadIdx.x;
    if (tid < H) {
        float s = 0.f;
        for (int c = 0; c < 64; c++) s += gs[c * H + tid];
        gg[tid] = s;
    }
    __syncthreads();
    if (tid < 16) {
        float s = bl1[tid];
        #pragma unroll
        for (int k = 0; k < 32; k++) s += gg[k] * Wl1[k * 16 + tid];
        t[tid] = fmaxf(s, 0.f);
    }
    __syncthreads();
    if (tid < 3) {
        float s = bl2[tid];
        #pragma unroll
        for (int k = 0; k < 16; k++) s += t[k] * Wl2[k * 3 + tid];
        out[tid] = s;
    }
}

extern "C" void kernel_launch(void* const* d_in, const int* in_sizes, int n_in,
                              void* d_out, int out_size, void* d_ws, size_t ws_size,
                              hipStream_t stream) {
    const float* x   = (const float*)d_in[0];
    const int*   ei  = (const int*)d_in[1];
    const float* W1  = (const float*)d_in[2];
    const float* b1  = (const float*)d_in[3];
    const float* W2  = (const float*)d_in[4];
    const float* b2  = (const float*)d_in[5];
    const float* W3  = (const float*)d_in[6];
    const float* b3  = (const float*)d_in[7];
    const float* W4  = (const float*)d_in[8];
    const float* b4  = (const float*)d_in[9];
    const float* Wl1 = (const float*)d_in[10];
    const float* bl1 = (const float*)d_in[11];
    const float* Wl2 = (const float*)d_in[12];
    const float* bl2 = (const float*)d_in[13];
    float* out = (float*)d_out;

    const int N = in_sizes[0] / F_IN;
    const int E = in_sizes[1] / 2;

    char* ws = (char*)d_ws;
    size_t off = 0;
    auto alloc = [&](size_t bytes) {
        char* p = ws + off;
        off += (bytes + 255) & ~(size_t)255;
        return p;
    };
    int*   deg         = (int*)alloc((size_t)N * 4);
    float* dinv        = (float*)alloc((size_t)N * 4);
    int*   scanned     = (int*)alloc((size_t)N * 4);
    int*   btot        = (int*)alloc(((size_t)N / 256 + 2) * 4);
    int*   row_start   = (int*)alloc((size_t)(N + 1) * 4);
    int*   cursor      = (int*)alloc((size_t)N * 4);
    int*   src_sorted  = (int*)alloc((size_t)E * 4);
    float* norm_sorted = (float*)alloc((size_t)E * 4);
    float* bufA        = (float*)alloc((size_t)N * H * 4);
    float* bufB        = (float*)alloc((size_t)N * H * 4);
    float* gs          = (float*)alloc(64 * H * 4);

    const int TB = 256;
    const int gE  = (E + TB - 1) / TB;
    const int gN  = (N + TB - 1) / TB;   // scan blocks (<=1024 for N<=262144)
    const int gNode = (N + 7) / 8;

    // ---- CSR build ----
    hipMemsetAsync(deg, 0, (size_t)N * 4, stream);
    hipMemsetAsync(cursor, 0, (size_t)N * 4, stream);
    hipMemsetAsync(gs, 0, 64 * H * 4, stream);
    deg_kernel<<<gE, TB, 0, stream>>>(ei, deg, E);
    dinv_kernel<<<gN, TB, 0, stream>>>(deg, dinv, N);
    scan1_kernel<<<gN, TB, 0, stream>>>(deg, scanned, btot, N);
    scan2_kernel<<<1, 1024, 0, stream>>>(btot, gN);
    scan3_kernel<<<gN, TB, 0, stream>>>(scanned, btot, row_start, N, E);
    scatter_kernel<<<NSLICE * MCHUNK, TB, 0, stream>>>(ei, row_start, cursor, dinv,
                                                       src_sorted, norm_sorted, E, N);

    // ---- layers ----
    gemm1_kernel<<<gNode, TB, 0, stream>>>(x, W1, bufA, N);                       // h1
    agg_gemm_kernel<<<gNode, TB, 0, stream>>>(row_start, src_sorted, norm_sorted,
                                              dinv, bufA, b1, W2, bufB, N);       // h2
    agg_gemm_kernel<<<gNode, TB, 0, stream>>>(row_start, src_sorted, norm_sorted,
                                              dinv, bufB, b2, W3, bufA, N);       // h3
    agg_gemm_kernel<<<gNode, TB, 0, stream>>>(row_start, src_sorted, norm_sorted,
                                              dinv, bufA, b3, W4, bufB, N);       // h4
    agg_pool_kernel<<<gNode, TB, 0, stream>>>(row_start, src_sorted, norm_sorted,
                                              dinv, bufB, b4, gs, N);             // pool(X5)

    head_kernel<<<1, 64, 0, stream>>>(gs, Wl1, bl1, Wl2, bl2, out);
}